// Round 1
// baseline (779.518 us; speedup 1.0000x reference)
//
#include <hip/hip_runtime.h>

typedef _Float16 f16;
typedef _Float16 f16x4 __attribute__((ext_vector_type(4)));
typedef _Float16 f16x8 __attribute__((ext_vector_type(8)));
typedef float    f32x4 __attribute__((ext_vector_type(4)));

#define NB    32
#define FEAT  320
#define NPTS  2048
#define M1    (NB * FEAT)          // 10240
#define KDIM  2048

// async global->LDS, 16B per lane. HW: dest = wave-uniform base + lane*16.
__device__ __forceinline__ void stage16(f16* lds_base, const f16* g, int lane) {
#if defined(__has_builtin) && __has_builtin(__builtin_amdgcn_global_load_lds)
    __builtin_amdgcn_global_load_lds(
        (const __attribute__((address_space(1))) void*)g,
        (__attribute__((address_space(3))) void*)lds_base, 16, 0, 0);
#else
    *(f16x8*)(lds_base + lane * 8) = *(const f16x8*)g;
#endif
}

// ---------------- cast fp32 -> f16 ----------------
__global__ void cast_k(const float* __restrict__ src, f16* __restrict__ dst, int n4) {
    int i = blockIdx.x * blockDim.x + threadIdx.x;
    int stride = gridDim.x * blockDim.x;
    for (; i < n4; i += stride) {
        f32x4 v = *(const f32x4*)(src + (size_t)i * 4);
        f16x4 h = __builtin_convertvector(v, f16x4);
        *(f16x4*)(dst + (size_t)i * 4) = h;
    }
}

// ---------------- GEMM1: C[m,n] = sum_k A[m,k] * W[n,k]  (both K-major) ----
// M=10240 N=2048 K=2048, 128x128 tile, BK=32, z selects (A,W,C) triple.
__global__ __launch_bounds__(256, 2) void gemm1_k(
    const f16* __restrict__ sq, const f16* __restrict__ qr,
    const f16* __restrict__ wq, const f16* __restrict__ wk, const f16* __restrict__ wv,
    f16* __restrict__ qq, f16* __restrict__ kk, f16* __restrict__ vv) {
    __shared__ f16 As[128 * 32];
    __shared__ f16 Bs[128 * 32];
    const int z = blockIdx.z;
    const f16* A = (z == 0) ? sq : qr;
    const f16* W = (z == 0) ? wq : (z == 1) ? wk : wv;
    f16* C       = (z == 0) ? qq : (z == 1) ? kk : vv;

    const int tid  = threadIdx.x;
    const int lane = tid & 63;
    const int w    = tid >> 6;
    const int wm   = w >> 1, wn = w & 1;
    const int lo   = lane & 15, q4 = lane >> 4;
    const long tm = (long)blockIdx.y * 128;
    const long tn = (long)blockIdx.x * 128;
    const f16* Abase = A + tm * KDIM;
    const f16* Bbase = W + tn * KDIM;

    f32x4 acc[4][4] = {};
    const int e0 = w * 64 + lane;

    for (int k0 = 0; k0 < KDIM; k0 += 32) {
#pragma unroll
        for (int j = 0; j < 2; ++j) {
            int e = j * 256 + e0;
            int row = e >> 2, ch = e & 3;
            stage16(&As[j * 2048 + w * 512], Abase + (long)row * KDIM + k0 + ch * 8, lane);
            stage16(&Bs[j * 2048 + w * 512], Bbase + (long)row * KDIM + k0 + ch * 8, lane);
        }
        __syncthreads();
        f16x8 af[4], bf[4];
#pragma unroll
        for (int mi = 0; mi < 4; ++mi)
            af[mi] = *(const f16x8*)&As[(wm * 64 + mi * 16 + lo) * 32 + q4 * 8];
#pragma unroll
        for (int ni = 0; ni < 4; ++ni)
            bf[ni] = *(const f16x8*)&Bs[(wn * 64 + ni * 16 + lo) * 32 + q4 * 8];
#pragma unroll
        for (int mi = 0; mi < 4; ++mi)
#pragma unroll
            for (int ni = 0; ni < 4; ++ni)
                acc[mi][ni] = __builtin_amdgcn_mfma_f32_16x16x32_f16(af[mi], bf[ni], acc[mi][ni], 0, 0, 0);
        __syncthreads();
    }
#pragma unroll
    for (int mi = 0; mi < 4; ++mi)
#pragma unroll
        for (int ni = 0; ni < 4; ++ni) {
            long gc = tn + wn * 64 + ni * 16 + lo;
#pragma unroll
            for (int r = 0; r < 4; ++r) {
                long gr = tm + wm * 64 + mi * 16 + q4 * 4 + r;
                C[gr * KDIM + gc] = (f16)acc[mi][ni][r];
            }
        }
}

// ---------------- transpose v_all [10240,2048] -> vT [32][2048][320] -------
__global__ void transpose_v(const f16* __restrict__ vv, f16* __restrict__ vT) {
    __shared__ f16 T[64][80];   // pad to 160B rows (16B aligned, bank-shifted)
    const int b = blockIdx.z;
    const int f0 = blockIdx.y * 64, o0 = blockIdx.x * 64;
    const int tid = threadIdx.x;
#pragma unroll
    for (int j = 0; j < 2; ++j) {
        int e = tid * 2 + j;            // 512 chunks of 8
        int r = e >> 3, c = e & 7;
        *(f16x8*)&T[r][c * 8] =
            *(const f16x8*)&vv[((size_t)b * FEAT + f0 + r) * NPTS + o0 + c * 8];
    }
    __syncthreads();
#pragma unroll
    for (int j = 0; j < 2; ++j) {
        int e = tid * 2 + j;
        int o = e >> 3, fc = e & 7;
        f16x8 val;
#pragma unroll
        for (int jj = 0; jj < 8; ++jj) val[jj] = T[fc * 8 + jj][o];
        *(f16x8*)&vT[(size_t)b * (NPTS * FEAT) + (size_t)(o0 + o) * FEAT + f0 + fc * 8] = val;
    }
}

// ---------------- GEMM2: attn[b,l,m] = (1/sqrt(320)) sum_o q[l,o]k[m,o] ----
__global__ __launch_bounds__(256, 2) void attn_gemm(
    const f16* __restrict__ qq, const f16* __restrict__ kk, float* __restrict__ attn) {
    __shared__ f16 As[64 * 32];
    __shared__ f16 Bs[64 * 32];
    const int b = blockIdx.z;
    const long tl = (long)blockIdx.y * 64, tmm = (long)blockIdx.x * 64;
    const int tid = threadIdx.x, lane = tid & 63, w = tid >> 6;
    const int wm = w >> 1, wn = w & 1, lo = lane & 15, q4 = lane >> 4;
    const f16* Abase = qq + ((long)b * FEAT + tl) * KDIM;
    const f16* Bbase = kk + ((long)b * FEAT + tmm) * KDIM;
    const int e = w * 64 + lane, row = e >> 2, ch = e & 3;

    f32x4 acc[2][2] = {};
    for (int k0 = 0; k0 < KDIM; k0 += 32) {
        stage16(&As[w * 512], Abase + (long)row * KDIM + k0 + ch * 8, lane);
        stage16(&Bs[w * 512], Bbase + (long)row * KDIM + k0 + ch * 8, lane);
        __syncthreads();
        f16x8 af[2], bf[2];
#pragma unroll
        for (int mi = 0; mi < 2; ++mi)
            af[mi] = *(const f16x8*)&As[(wm * 32 + mi * 16 + lo) * 32 + q4 * 8];
#pragma unroll
        for (int ni = 0; ni < 2; ++ni)
            bf[ni] = *(const f16x8*)&Bs[(wn * 32 + ni * 16 + lo) * 32 + q4 * 8];
#pragma unroll
        for (int mi = 0; mi < 2; ++mi)
#pragma unroll
            for (int ni = 0; ni < 2; ++ni)
                acc[mi][ni] = __builtin_amdgcn_mfma_f32_16x16x32_f16(af[mi], bf[ni], acc[mi][ni], 0, 0, 0);
        __syncthreads();
    }
    const float scale = 0.05590169943749474f;  // 1/sqrt(320)
#pragma unroll
    for (int mi = 0; mi < 2; ++mi)
#pragma unroll
        for (int ni = 0; ni < 2; ++ni) {
            long gm = tmm + wn * 32 + ni * 16 + lo;
#pragma unroll
            for (int r = 0; r < 4; ++r) {
                long gl = tl + wm * 32 + mi * 16 + q4 * 4 + r;
                attn[(long)b * (FEAT * FEAT) + gl * FEAT + gm] = acc[mi][ni][r] * scale;
            }
        }
}

// ---------------- softmax over rows of 320, fp32 in, f16 probs out ---------
__global__ void softmax_k(const float* __restrict__ attn, f16* __restrict__ probs) {
    const int r = blockIdx.x * 4 + (threadIdx.x >> 6);   // 10240 rows
    const int lane = threadIdx.x & 63;
    const float* row = attn + (size_t)r * FEAT;
    float v[5];
    float mx = -1e30f;
#pragma unroll
    for (int j = 0; j < 5; ++j) { v[j] = row[lane + j * 64]; mx = fmaxf(mx, v[j]); }
#pragma unroll
    for (int off = 32; off; off >>= 1) mx = fmaxf(mx, __shfl_xor(mx, off, 64));
    float s = 0.f;
#pragma unroll
    for (int j = 0; j < 5; ++j) { v[j] = __expf(v[j] - mx); s += v[j]; }
#pragma unroll
    for (int off = 32; off; off >>= 1) s += __shfl_xor(s, off, 64);
    const float inv = 1.f / s;
    f16* prow = probs + (size_t)r * FEAT;
#pragma unroll
    for (int j = 0; j < 5; ++j) prow[lane + j * 64] = (f16)(v[j] * inv);
}

// ---------------- GEMM3: out[b,l,o] = sum_m P[l,m] vT[o,m] + query[b,l,o] --
__global__ __launch_bounds__(256, 2) void pv_gemm(
    const f16* __restrict__ probs, const f16* __restrict__ vT,
    const float* __restrict__ query, float* __restrict__ out) {
    __shared__ f16 As[64 * 32];
    __shared__ f16 Bs[64 * 32];
    const int b = blockIdx.z;
    const long tl = (long)blockIdx.y * 64, to = (long)blockIdx.x * 64;
    const int tid = threadIdx.x, lane = tid & 63, w = tid >> 6;
    const int wm = w >> 1, wn = w & 1, lo = lane & 15, q4 = lane >> 4;
    const f16* Abase = probs + (long)b * (FEAT * FEAT) + tl * FEAT;
    const f16* Bbase = vT + (long)b * (NPTS * FEAT) + to * FEAT;
    const int e = w * 64 + lane, row = e >> 2, ch = e & 3;

    f32x4 acc[2][2] = {};
    for (int k0 = 0; k0 < FEAT; k0 += 32) {   // 10 iterations
        stage16(&As[w * 512], Abase + (long)row * FEAT + k0 + ch * 8, lane);
        stage16(&Bs[w * 512], Bbase + (long)row * FEAT + k0 + ch * 8, lane);
        __syncthreads();
        f16x8 af[2], bf[2];
#pragma unroll
        for (int mi = 0; mi < 2; ++mi)
            af[mi] = *(const f16x8*)&As[(wm * 32 + mi * 16 + lo) * 32 + q4 * 8];
#pragma unroll
        for (int ni = 0; ni < 2; ++ni)
            bf[ni] = *(const f16x8*)&Bs[(wn * 32 + ni * 16 + lo) * 32 + q4 * 8];
#pragma unroll
        for (int mi = 0; mi < 2; ++mi)
#pragma unroll
            for (int ni = 0; ni < 2; ++ni)
                acc[mi][ni] = __builtin_amdgcn_mfma_f32_16x16x32_f16(af[mi], bf[ni], acc[mi][ni], 0, 0, 0);
        __syncthreads();
    }
#pragma unroll
    for (int mi = 0; mi < 2; ++mi)
#pragma unroll
        for (int ni = 0; ni < 2; ++ni) {
            long go = to + wn * 32 + ni * 16 + lo;
#pragma unroll
            for (int r = 0; r < 4; ++r) {
                long gl = tl + wm * 32 + mi * 16 + q4 * 4 + r;
                size_t idx = (size_t)b * (FEAT * NPTS) + (size_t)gl * NPTS + go;
                out[idx] = acc[mi][ni][r] + query[idx];
            }
        }
}

// ---------------- in-place LayerNorm over FEAT (stride NPTS) ---------------
__global__ void ln_k(float* __restrict__ out, const float* __restrict__ gamma,
                     const float* __restrict__ beta) {
    __shared__ float g[FEAT], bt[FEAT];
    const int tid = threadIdx.x;
    for (int i = tid; i < FEAT; i += 256) { g[i] = gamma[i]; bt[i] = beta[i]; }
    __syncthreads();
    const int col = blockIdx.x * 256 + tid;     // 65536 columns
    const int b = col >> 11, o = col & 2047;
    float* base = out + (size_t)b * (FEAT * NPTS) + o;
    float s = 0.f, ss = 0.f;
    for (int l = 0; l < FEAT; ++l) {
        float x = base[(size_t)l * NPTS];
        s += x; ss += x * x;
    }
    const float mu = s * (1.f / FEAT);
    const float var = ss * (1.f / FEAT) - mu * mu;
    const float rstd = rsqrtf(var + 1e-5f);
    for (int l = 0; l < FEAT; ++l) {
        float x = base[(size_t)l * NPTS];
        base[(size_t)l * NPTS] = (x - mu) * rstd * g[l] + bt[l];
    }
}

extern "C" void kernel_launch(void* const* d_in, const int* in_sizes, int n_in,
                              void* d_out, int out_size, void* d_ws, size_t ws_size,
                              hipStream_t stream) {
    const float* query   = (const float*)d_in[0];
    const float* support = (const float*)d_in[1];
    const float* Wq      = (const float*)d_in[2];
    const float* Wk      = (const float*)d_in[3];
    const float* Wv      = (const float*)d_in[4];
    const float* gamma   = (const float*)d_in[5];
    const float* beta    = (const float*)d_in[6];
    float* out = (float*)d_out;

    char* ws = (char*)d_ws;
    const size_t SZ_X = (size_t)M1 * KDIM * sizeof(f16);     // 41,943,040
    const size_t SZ_W = (size_t)KDIM * KDIM * sizeof(f16);   //  8,388,608
    f16* sq = (f16*)(ws);                       // support f16
    f16* qr = (f16*)(ws + SZ_X);                // query f16
    f16* wq = (f16*)(ws + 2 * SZ_X);
    f16* wk = (f16*)(ws + 2 * SZ_X + SZ_W);
    f16* wv = (f16*)(ws + 2 * SZ_X + 2 * SZ_W);
    f16* qq = (f16*)(ws + 2 * SZ_X + 3 * SZ_W);             // q_all
    f16* kk = (f16*)(ws + 3 * SZ_X + 3 * SZ_W);             // k_all
    f16* vv = (f16*)(ws + 4 * SZ_X + 3 * SZ_W);             // v_all
    // reuse regions (stream-ordered, originals dead by then):
    f16*   vT    = sq;                                        // [32][2048][320]
    float* attn  = (float*)(ws + SZ_X);                       // over qr, 13,107,200 B
    f16*   probs = (f16*)(ws + SZ_X + (size_t)NB * FEAT * FEAT * 4);

    const int nX4 = (M1 * KDIM) / 4;        // 5,242,880
    const int nW4 = (KDIM * KDIM) / 4;      // 1,048,576
    cast_k<<<2048, 256, 0, stream>>>(support, sq, nX4);
    cast_k<<<2048, 256, 0, stream>>>(query, qr, nX4);
    cast_k<<<1024, 256, 0, stream>>>(Wq, wq, nW4);
    cast_k<<<1024, 256, 0, stream>>>(Wk, wk, nW4);
    cast_k<<<1024, 256, 0, stream>>>(Wv, wv, nW4);

    gemm1_k<<<dim3(16, 80, 3), 256, 0, stream>>>(sq, qr, wq, wk, wv, qq, kk, vv);
    transpose_v<<<dim3(32, 5, 32), 256, 0, stream>>>(vv, vT);
    attn_gemm<<<dim3(5, 5, 32), 256, 0, stream>>>(qq, kk, attn);
    softmax_k<<<2560, 256, 0, stream>>>(attn, probs);
    pv_gemm<<<dim3(32, 5, 32), 256, 0, stream>>>(probs, vT, query, out);
    ln_k<<<256, 256, 0, stream>>>(out, gamma, beta);
}

// Round 2
// 740.934 us; speedup vs baseline: 1.0521x; 1.0521x over previous
//
#include <hip/hip_runtime.h>

typedef _Float16 f16;
typedef _Float16 f16x4 __attribute__((ext_vector_type(4)));
typedef _Float16 f16x8 __attribute__((ext_vector_type(8)));
typedef float    f32x4 __attribute__((ext_vector_type(4)));

#define NB    32
#define FEAT  320
#define NPTS  2048
#define M1    (NB * FEAT)          // 10240
#define KDIM  2048

// async global->LDS, 16B per lane. HW: dest = wave-uniform base + lane*16.
__device__ __forceinline__ void stage16(f16* lds_base, const f16* g, int lane) {
    __builtin_amdgcn_global_load_lds(
        (const __attribute__((address_space(1))) void*)g,
        (__attribute__((address_space(3))) void*)lds_base, 16, 0, 0);
}

// ---------------- cast fp32 -> f16 (straight) ----------------
__global__ void cast_k(const float* __restrict__ src, f16* __restrict__ dst, int n4) {
    int i = blockIdx.x * blockDim.x + threadIdx.x;
    int stride = gridDim.x * blockDim.x;
    for (; i < n4; i += stride) {
        f32x4 v = *(const f32x4*)(src + (size_t)i * 4);
        *(f16x4*)(dst + (size_t)i * 4) = __builtin_convertvector(v, f16x4);
    }
}

// ------------- transpose-cast W [o,i] fp32 -> WT [i,o] f16, z picks Wq/Wk --
__global__ void castT_k(const float* __restrict__ Wq, const float* __restrict__ Wk,
                        f16* __restrict__ WqT, f16* __restrict__ WkT) {
    __shared__ float T[64][65];
    const float* W = blockIdx.z ? Wk : Wq;
    f16* WT        = blockIdx.z ? WkT : WqT;
    const int i0 = blockIdx.x * 64, o0 = blockIdx.y * 64;
    const int tid = threadIdx.x;
#pragma unroll
    for (int j = 0; j < 4; ++j) {
        int e = j * 256 + tid, r = e >> 4, c4 = e & 15;
        f32x4 v = *(const f32x4*)&W[(size_t)(o0 + r) * 2048 + i0 + c4 * 4];
        *(f32x4*)&T[r][c4 * 4] = v;
    }
    __syncthreads();
#pragma unroll
    for (int j = 0; j < 2; ++j) {
        int e = j * 256 + tid, ir = e >> 3, oc8 = e & 7;
        f16x8 val;
#pragma unroll
        for (int k = 0; k < 8; ++k) val[k] = (f16)T[oc8 * 8 + k][ir];
        *(f16x8*)&WT[(size_t)(i0 + ir) * 2048 + o0 + oc8 * 8] = val;
    }
}

// ------- query [b,m,j] fp32 -> qf16 [b,m,j] + qT16 [b,j,m], both f16 -------
__global__ void cast_q_dual(const float* __restrict__ q, f16* __restrict__ qf16,
                            f16* __restrict__ qT16) {
    __shared__ float T[64][65];
    const int b = blockIdx.z;
    const int j0 = blockIdx.x * 64, m0 = blockIdx.y * 64;  // m0 in [0,320)
    const int tid = threadIdx.x;
#pragma unroll
    for (int j = 0; j < 4; ++j) {
        int e = j * 256 + tid, r = e >> 4, c4 = e & 15;
        size_t src = ((size_t)b * FEAT + m0 + r) * NPTS + j0 + c4 * 4;
        f32x4 v = *(const f32x4*)&q[src];
        *(f32x4*)&T[r][c4 * 4] = v;
        *(f16x4*)&qf16[src] = __builtin_convertvector(v, f16x4);
    }
    __syncthreads();
#pragma unroll
    for (int j = 0; j < 2; ++j) {
        int e = j * 256 + tid, jr = e >> 3, mc8 = e & 7;
        f16x8 val;
#pragma unroll
        for (int k = 0; k < 8; ++k) val[k] = (f16)T[mc8 * 8 + k][jr];
        *(f16x8*)&qT16[((size_t)b * NPTS + j0 + jr) * FEAT + m0 + mc8 * 8] = val;
    }
}

// -------- 128x128 bt-GEMM, K=2048: C[m,n] = scale * sum_k A[m,k]B[n,k] ----
__global__ __launch_bounds__(256, 2) void gemm128_f16(
    const f16* __restrict__ A, const f16* __restrict__ B, f16* __restrict__ C,
    float scale) {
    __shared__ f16 As[128 * 32];
    __shared__ f16 Bs[128 * 32];
    const int tid = threadIdx.x, lane = tid & 63, w = tid >> 6;
    const int wm = w >> 1, wn = w & 1, lo = lane & 15, q4 = lane >> 4;
    const long tm = (long)blockIdx.y * 128, tn = (long)blockIdx.x * 128;
    const f16* Abase = A + tm * KDIM;
    const f16* Bbase = B + tn * KDIM;
    f32x4 acc[4][4] = {};
    const int e0 = w * 64 + lane;
    for (int k0 = 0; k0 < KDIM; k0 += 32) {
#pragma unroll
        for (int j = 0; j < 2; ++j) {
            int e = j * 256 + e0, row = e >> 2, ch = e & 3;
            stage16(&As[j * 2048 + w * 512], Abase + (long)row * KDIM + k0 + ch * 8, lane);
            stage16(&Bs[j * 2048 + w * 512], Bbase + (long)row * KDIM + k0 + ch * 8, lane);
        }
        __syncthreads();
        f16x8 af[4], bf[4];
#pragma unroll
        for (int mi = 0; mi < 4; ++mi)
            af[mi] = *(const f16x8*)&As[(wm * 64 + mi * 16 + lo) * 32 + q4 * 8];
#pragma unroll
        for (int ni = 0; ni < 4; ++ni)
            bf[ni] = *(const f16x8*)&Bs[(wn * 64 + ni * 16 + lo) * 32 + q4 * 8];
#pragma unroll
        for (int mi = 0; mi < 4; ++mi)
#pragma unroll
            for (int ni = 0; ni < 4; ++ni)
                acc[mi][ni] = __builtin_amdgcn_mfma_f32_16x16x32_f16(af[mi], bf[ni], acc[mi][ni], 0, 0, 0);
        __syncthreads();
    }
#pragma unroll
    for (int mi = 0; mi < 4; ++mi)
#pragma unroll
        for (int ni = 0; ni < 4; ++ni) {
            long gc = tn + wn * 64 + ni * 16 + lo;
#pragma unroll
            for (int r = 0; r < 4; ++r) {
                long gr = tm + wm * 64 + mi * 16 + q4 * 4 + r;
                C[gr * KDIM + gc] = (f16)(acc[mi][ni][r] * scale);
            }
        }
}

// -------- 128x128 bt-GEMM + residual: out = A·B^T + query (fp32) ----------
__global__ __launch_bounds__(256, 2) void gemm128_res(
    const f16* __restrict__ A, const f16* __restrict__ B,
    const float* __restrict__ query, float* __restrict__ out) {
    __shared__ f16 As[128 * 32];
    __shared__ f16 Bs[128 * 32];
    const int tid = threadIdx.x, lane = tid & 63, w = tid >> 6;
    const int wm = w >> 1, wn = w & 1, lo = lane & 15, q4 = lane >> 4;
    const long tm = (long)blockIdx.y * 128, tn = (long)blockIdx.x * 128;
    const f16* Abase = A + tm * KDIM;
    const f16* Bbase = B + tn * KDIM;
    f32x4 acc[4][4] = {};
    const int e0 = w * 64 + lane;
    for (int k0 = 0; k0 < KDIM; k0 += 32) {
#pragma unroll
        for (int j = 0; j < 2; ++j) {
            int e = j * 256 + e0, row = e >> 2, ch = e & 3;
            stage16(&As[j * 2048 + w * 512], Abase + (long)row * KDIM + k0 + ch * 8, lane);
            stage16(&Bs[j * 2048 + w * 512], Bbase + (long)row * KDIM + k0 + ch * 8, lane);
        }
        __syncthreads();
        f16x8 af[4], bf[4];
#pragma unroll
        for (int mi = 0; mi < 4; ++mi)
            af[mi] = *(const f16x8*)&As[(wm * 64 + mi * 16 + lo) * 32 + q4 * 8];
#pragma unroll
        for (int ni = 0; ni < 4; ++ni)
            bf[ni] = *(const f16x8*)&Bs[(wn * 64 + ni * 16 + lo) * 32 + q4 * 8];
#pragma unroll
        for (int mi = 0; mi < 4; ++mi)
#pragma unroll
            for (int ni = 0; ni < 4; ++ni)
                acc[mi][ni] = __builtin_amdgcn_mfma_f32_16x16x32_f16(af[mi], bf[ni], acc[mi][ni], 0, 0, 0);
        __syncthreads();
    }
#pragma unroll
    for (int mi = 0; mi < 4; ++mi)
#pragma unroll
        for (int ni = 0; ni < 4; ++ni) {
            long gc = tn + wn * 64 + ni * 16 + lo;
#pragma unroll
            for (int r = 0; r < 4; ++r) {
                long gr = tm + wm * 64 + mi * 16 + q4 * 4 + r;
                size_t idx = (size_t)gr * KDIM + gc;
                out[idx] = acc[mi][ni][r] + query[idx];
            }
        }
}

// ---- 64x64 bt-GEMM batched: attn[b,l,m] = sum_j T[b,l,j]·qf16[b,m,j] -----
__global__ __launch_bounds__(256, 2) void attn_gemm(
    const f16* __restrict__ T, const f16* __restrict__ qf16, float* __restrict__ attn) {
    __shared__ f16 As[64 * 32];
    __shared__ f16 Bs[64 * 32];
    const int b = blockIdx.z;
    const long tl = (long)blockIdx.y * 64, tmm = (long)blockIdx.x * 64;
    const int tid = threadIdx.x, lane = tid & 63, w = tid >> 6;
    const int wm = w >> 1, wn = w & 1, lo = lane & 15, q4 = lane >> 4;
    const f16* Abase = T + ((long)b * FEAT + tl) * KDIM;
    const f16* Bbase = qf16 + ((long)b * FEAT + tmm) * KDIM;
    const int e = w * 64 + lane, row = e >> 2, ch = e & 3;
    f32x4 acc[2][2] = {};
    for (int k0 = 0; k0 < KDIM; k0 += 32) {
        stage16(&As[w * 512], Abase + (long)row * KDIM + k0 + ch * 8, lane);
        stage16(&Bs[w * 512], Bbase + (long)row * KDIM + k0 + ch * 8, lane);
        __syncthreads();
        f16x8 af[2], bf[2];
#pragma unroll
        for (int mi = 0; mi < 2; ++mi)
            af[mi] = *(const f16x8*)&As[(wm * 32 + mi * 16 + lo) * 32 + q4 * 8];
#pragma unroll
        for (int ni = 0; ni < 2; ++ni)
            bf[ni] = *(const f16x8*)&Bs[(wn * 32 + ni * 16 + lo) * 32 + q4 * 8];
#pragma unroll
        for (int mi = 0; mi < 2; ++mi)
#pragma unroll
            for (int ni = 0; ni < 2; ++ni)
                acc[mi][ni] = __builtin_amdgcn_mfma_f32_16x16x32_f16(af[mi], bf[ni], acc[mi][ni], 0, 0, 0);
        __syncthreads();
    }
#pragma unroll
    for (int mi = 0; mi < 2; ++mi)
#pragma unroll
        for (int ni = 0; ni < 2; ++ni) {
            long gm = tmm + wn * 32 + ni * 16 + lo;
#pragma unroll
            for (int r = 0; r < 4; ++r) {
                long gl = tl + wm * 32 + mi * 16 + q4 * 4 + r;
                attn[(long)b * (FEAT * FEAT) + gl * FEAT + gm] = acc[mi][ni][r];
            }
        }
}

// ---- 64x64 bt-GEMM batched, K=320: U[b,l,j] = sum_m P[b,l,m]·qT16[b,j,m] --
__global__ __launch_bounds__(256, 2) void u_gemm(
    const f16* __restrict__ P, const f16* __restrict__ qT16, f16* __restrict__ U) {
    __shared__ f16 As[64 * 32];
    __shared__ f16 Bs[64 * 32];
    const int b = blockIdx.z;
    const long tl = (long)blockIdx.y * 64, to = (long)blockIdx.x * 64;
    const int tid = threadIdx.x, lane = tid & 63, w = tid >> 6;
    const int wm = w >> 1, wn = w & 1, lo = lane & 15, q4 = lane >> 4;
    const f16* Abase = P + ((long)b * FEAT + tl) * FEAT;
    const f16* Bbase = qT16 + ((long)b * NPTS + to) * FEAT;
    const int e = w * 64 + lane, row = e >> 2, ch = e & 3;
    f32x4 acc[2][2] = {};
    for (int k0 = 0; k0 < FEAT; k0 += 32) {   // 10 iterations
        stage16(&As[w * 512], Abase + (long)row * FEAT + k0 + ch * 8, lane);
        stage16(&Bs[w * 512], Bbase + (long)row * FEAT + k0 + ch * 8, lane);
        __syncthreads();
        f16x8 af[2], bf[2];
#pragma unroll
        for (int mi = 0; mi < 2; ++mi)
            af[mi] = *(const f16x8*)&As[(wm * 32 + mi * 16 + lo) * 32 + q4 * 8];
#pragma unroll
        for (int ni = 0; ni < 2; ++ni)
            bf[ni] = *(const f16x8*)&Bs[(wn * 32 + ni * 16 + lo) * 32 + q4 * 8];
#pragma unroll
        for (int mi = 0; mi < 2; ++mi)
#pragma unroll
            for (int ni = 0; ni < 2; ++ni)
                acc[mi][ni] = __builtin_amdgcn_mfma_f32_16x16x32_f16(af[mi], bf[ni], acc[mi][ni], 0, 0, 0);
        __syncthreads();
    }
#pragma unroll
    for (int mi = 0; mi < 2; ++mi)
#pragma unroll
        for (int ni = 0; ni < 2; ++ni) {
            long go = to + wn * 32 + ni * 16 + lo;
#pragma unroll
            for (int r = 0; r < 4; ++r) {
                long gl = tl + wm * 32 + mi * 16 + q4 * 4 + r;
                U[((long)b * FEAT + gl) * NPTS + go] = (f16)acc[mi][ni][r];
            }
        }
}

// ---------------- softmax over rows of 320, fp32 in, f16 probs out ---------
__global__ void softmax_k(const float* __restrict__ attn, f16* __restrict__ probs) {
    const int r = blockIdx.x * 4 + (threadIdx.x >> 6);   // 10240 rows
    const int lane = threadIdx.x & 63;
    const float* row = attn + (size_t)r * FEAT;
    float v[5];
    float mx = -1e30f;
#pragma unroll
    for (int j = 0; j < 5; ++j) { v[j] = row[lane + j * 64]; mx = fmaxf(mx, v[j]); }
#pragma unroll
    for (int off = 32; off; off >>= 1) mx = fmaxf(mx, __shfl_xor(mx, off, 64));
    float s = 0.f;
#pragma unroll
    for (int j = 0; j < 5; ++j) { v[j] = __expf(v[j] - mx); s += v[j]; }
#pragma unroll
    for (int off = 32; off; off >>= 1) s += __shfl_xor(s, off, 64);
    const float inv = 1.f / s;
    f16* prow = probs + (size_t)r * FEAT;
#pragma unroll
    for (int j = 0; j < 5; ++j) prow[lane + j * 64] = (f16)(v[j] * inv);
}

// ---------------- in-place LayerNorm over FEAT (stride NPTS) ---------------
__global__ void ln_k(float* __restrict__ out, const float* __restrict__ gamma,
                     const float* __restrict__ beta) {
    __shared__ float g[FEAT], bt[FEAT];
    const int tid = threadIdx.x;
    for (int i = tid; i < FEAT; i += 256) { g[i] = gamma[i]; bt[i] = beta[i]; }
    __syncthreads();
    const int col = blockIdx.x * 256 + tid;     // 65536 columns
    const int b = col >> 11, o = col & 2047;
    float* base = out + (size_t)b * (FEAT * NPTS) + o;
    float s = 0.f, ss = 0.f;
    for (int l = 0; l < FEAT; ++l) {
        float x = base[(size_t)l * NPTS];
        s += x; ss += x * x;
    }
    const float mu = s * (1.f / FEAT);
    const float var = ss * (1.f / FEAT) - mu * mu;
    const float rstd = rsqrtf(var + 1e-5f);
    for (int l = 0; l < FEAT; ++l) {
        float x = base[(size_t)l * NPTS];
        base[(size_t)l * NPTS] = (x - mu) * rstd * g[l] + bt[l];
    }
}

extern "C" void kernel_launch(void* const* d_in, const int* in_sizes, int n_in,
                              void* d_out, int out_size, void* d_ws, size_t ws_size,
                              hipStream_t stream) {
    const float* query   = (const float*)d_in[0];
    const float* support = (const float*)d_in[1];
    const float* Wq      = (const float*)d_in[2];
    const float* Wk      = (const float*)d_in[3];
    const float* Wv      = (const float*)d_in[4];
    const float* gamma   = (const float*)d_in[5];
    const float* beta    = (const float*)d_in[6];
    float* out = (float*)d_out;

    char* ws = (char*)d_ws;
    const size_t SZ_W = (size_t)KDIM * KDIM * sizeof(f16);   //  8,388,608
    const size_t SZ_X = (size_t)M1 * KDIM * sizeof(f16);     // 41,943,040
    f16* wqT  = (f16*)(ws);                        // [i,o]
    f16* wkT  = (f16*)(ws + SZ_W);                 // [j,o]
    f16* wv16 = (f16*)(ws + 2 * SZ_W);             // [o,j] straight
    f16* gt   = (f16*)(ws + 3 * SZ_W);             // Gt[j,i] = G[i,j]/TEMP
    f16* sf16 = (f16*)(ws + 4 * SZ_W);             // support f16 [b*320, i]
    f16* qf16 = (f16*)(ws + 4 * SZ_W + SZ_X);      // [b,m,j]
    f16* qT16 = (f16*)(ws + 4 * SZ_W + 2 * SZ_X);  // [b,j,m]
    f16* T    = (f16*)(ws + 4 * SZ_W + 3 * SZ_X);  // [b*320, j]
    // overlays (stream-ordered; originals dead by first write):
    float* attn = (float*)(ws);                    // 13.1 MB over wqT+wkT (dead after g_gemm)
    f16*   P    = qf16;                            // probs (qf16 dead after attn_gemm)
    f16*   U    = sf16;                            // U[b,l,j] (sf16 dead after t_gemm)

    const float inv_temp = 0.05590169943749474f;   // 1/sqrt(320)

    castT_k<<<dim3(32, 32, 2), 256, 0, stream>>>(Wq, Wk, wqT, wkT);
    cast_k<<<1024, 256, 0, stream>>>(Wv, wv16, (KDIM * KDIM) / 4);
    cast_k<<<2048, 256, 0, stream>>>(support, sf16, (M1 * KDIM) / 4);
    cast_q_dual<<<dim3(32, 5, 32), 256, 0, stream>>>(query, qf16, qT16);

    // Gt[j,i] = (1/TEMP) * sum_o WkT[j,o] * WqT[i,o]
    gemm128_f16<<<dim3(16, 16), 256, 0, stream>>>(wkT, wqT, gt, inv_temp);
    // T[(b,l), j] = sum_i sf16[(b,l), i] * Gt[j, i]
    gemm128_f16<<<dim3(16, 80), 256, 0, stream>>>(sf16, gt, T, 1.0f);
    // logits
    attn_gemm<<<dim3(5, 5, 32), 256, 0, stream>>>(T, qf16, attn);
    softmax_k<<<2560, 256, 0, stream>>>(attn, P);
    // U[b,l,j] = sum_m P[b,l,m] * qT16[b,j,m]
    u_gemm<<<dim3(32, 5, 32), 256, 0, stream>>>(P, qT16, U);
    // out = U * Wv^T + query
    gemm128_res<<<dim3(16, 80), 256, 0, stream>>>(U, wv16, query, out);
    ln_k<<<256, 256, 0, stream>>>(out, gamma, beta);
}

// Round 3
// 700.989 us; speedup vs baseline: 1.1120x; 1.0570x over previous
//
#include <hip/hip_runtime.h>

typedef _Float16 f16;
typedef _Float16 f16x4 __attribute__((ext_vector_type(4)));
typedef _Float16 f16x8 __attribute__((ext_vector_type(8)));
typedef float    f32x4 __attribute__((ext_vector_type(4)));

#define NB    32
#define FEAT  320
#define NPTS  2048
#define M1    (NB * FEAT)          // 10240
#define KDIM  2048

// async global->LDS, 16B per lane. LDS dest = wave-uniform base + lane*16.
__device__ __forceinline__ void stage16(f16* lds_base, const f16* g) {
    __builtin_amdgcn_global_load_lds(
        (const __attribute__((address_space(1))) void*)g,
        (__attribute__((address_space(3))) void*)lds_base, 16, 0, 0);
}

// ---------------- cast fp32 -> f16 (straight) ----------------
__global__ void cast_k(const float* __restrict__ src, f16* __restrict__ dst, int n4) {
    int i = blockIdx.x * blockDim.x + threadIdx.x;
    int stride = gridDim.x * blockDim.x;
    for (; i < n4; i += stride) {
        f32x4 v = *(const f32x4*)(src + (size_t)i * 4);
        *(f16x4*)(dst + (size_t)i * 4) = __builtin_convertvector(v, f16x4);
    }
}

// ------------- transpose-cast W [o,i] fp32 -> WT [i,o] f16, z picks Wq/Wk --
__global__ void castT_k(const float* __restrict__ Wq, const float* __restrict__ Wk,
                        f16* __restrict__ WqT, f16* __restrict__ WkT) {
    __shared__ float T[64][65];
    const float* W = blockIdx.z ? Wk : Wq;
    f16* WT        = blockIdx.z ? WkT : WqT;
    const int i0 = blockIdx.x * 64, o0 = blockIdx.y * 64;
    const int tid = threadIdx.x;
#pragma unroll
    for (int j = 0; j < 4; ++j) {
        int e = j * 256 + tid, r = e >> 4, c4 = e & 15;
        f32x4 v = *(const f32x4*)&W[(size_t)(o0 + r) * 2048 + i0 + c4 * 4];
        *(f32x4*)&T[r][c4 * 4] = v;
    }
    __syncthreads();
#pragma unroll
    for (int j = 0; j < 2; ++j) {
        int e = j * 256 + tid, ir = e >> 3, oc8 = e & 7;
        f16x8 val;
#pragma unroll
        for (int k = 0; k < 8; ++k) val[k] = (f16)T[oc8 * 8 + k][ir];
        *(f16x8*)&WT[(size_t)(i0 + ir) * 2048 + o0 + oc8 * 8] = val;
    }
}

// ------- query [b,m,j] fp32 -> qf16 [b,m,j] + qT16 [b,j,m], both f16 -------
__global__ void cast_q_dual(const float* __restrict__ q, f16* __restrict__ qf16,
                            f16* __restrict__ qT16) {
    __shared__ float T[64][65];
    const int b = blockIdx.z;
    const int j0 = blockIdx.x * 64, m0 = blockIdx.y * 64;  // m0 in [0,320)
    const int tid = threadIdx.x;
#pragma unroll
    for (int j = 0; j < 4; ++j) {
        int e = j * 256 + tid, r = e >> 4, c4 = e & 15;
        size_t src = ((size_t)b * FEAT + m0 + r) * NPTS + j0 + c4 * 4;
        f32x4 v = *(const f32x4*)&q[src];
        *(f32x4*)&T[r][c4 * 4] = v;
        *(f16x4*)&qf16[src] = __builtin_convertvector(v, f16x4);
    }
    __syncthreads();
#pragma unroll
    for (int j = 0; j < 2; ++j) {
        int e = j * 256 + tid, jr = e >> 3, mc8 = e & 7;
        f16x8 val;
#pragma unroll
        for (int k = 0; k < 8; ++k) val[k] = (f16)T[mc8 * 8 + k][jr];
        *(f16x8*)&qT16[((size_t)b * NPTS + j0 + jr) * FEAT + m0 + mc8 * 8] = val;
    }
}

// ======== 128x128 bt-GEMM, BK=64 (split-k-half LDS): C = scale*A·B^T =======
// LDS layout [2][128][32]: k-half h separated so fragment reads keep 64B row
// stride (m97 bank pattern). Staging: wave-unit u = w*4+j covers (h=u&1,
// 16 rows Rb=u>>1); lane -> row=Rb*16+lane/4, kchunk=lane%4. Dest contiguous.
__global__ __launch_bounds__(256, 2) void gemm128_f16(
    const f16* __restrict__ A, const f16* __restrict__ B, f16* __restrict__ C,
    float scale) {
    __shared__ f16 As[2 * 128 * 32];
    __shared__ f16 Bs[2 * 128 * 32];
    const int tid = threadIdx.x, lane = tid & 63, w = tid >> 6;
    const int wm = w >> 1, wn = w & 1, lo = lane & 15, q4 = lane >> 4;
    const long tm = (long)blockIdx.y * 128, tn = (long)blockIdx.x * 128;
    const f16* Abase = A + tm * KDIM;
    const f16* Bbase = B + tn * KDIM;
    f32x4 acc[4][4] = {};
    const int srow = lane >> 2, sch = (lane & 3) * 8;   // staging row/chunk in unit

    for (int k0 = 0; k0 < KDIM; k0 += 64) {
#pragma unroll
        for (int j = 0; j < 4; ++j) {
            const int u = w * 4 + j, h = u & 1, Rb = u >> 1;
            const int base = h * 4096 + Rb * 512;       // f16 offset
            const long grow = Rb * 16 + srow;
            const long gk = k0 + h * 32 + sch;
            stage16(&As[base], Abase + grow * KDIM + gk);
            stage16(&Bs[base], Bbase + grow * KDIM + gk);
        }
        __syncthreads();
        f16x8 af[4][2], bf[4][2];
#pragma unroll
        for (int s = 0; s < 2; ++s) {
#pragma unroll
            for (int mi = 0; mi < 4; ++mi)
                af[mi][s] = *(const f16x8*)&As[s * 4096 + (wm * 64 + mi * 16 + lo) * 32 + q4 * 8];
#pragma unroll
            for (int ni = 0; ni < 4; ++ni)
                bf[ni][s] = *(const f16x8*)&Bs[s * 4096 + (wn * 64 + ni * 16 + lo) * 32 + q4 * 8];
        }
#pragma unroll
        for (int s = 0; s < 2; ++s)
#pragma unroll
            for (int mi = 0; mi < 4; ++mi)
#pragma unroll
                for (int ni = 0; ni < 4; ++ni)
                    acc[mi][ni] = __builtin_amdgcn_mfma_f32_16x16x32_f16(af[mi][s], bf[ni][s], acc[mi][ni], 0, 0, 0);
        __syncthreads();
    }
#pragma unroll
    for (int mi = 0; mi < 4; ++mi)
#pragma unroll
        for (int ni = 0; ni < 4; ++ni) {
            long gc = tn + wn * 64 + ni * 16 + lo;
#pragma unroll
            for (int r = 0; r < 4; ++r) {
                long gr = tm + wm * 64 + mi * 16 + q4 * 4 + r;
                C[gr * KDIM + gc] = (f16)(acc[mi][ni][r] * scale);
            }
        }
}

// ======== 128x128 bt-GEMM BK=64 + residual: out = A·B^T + query (fp32) =====
__global__ __launch_bounds__(256, 2) void gemm128_res(
    const f16* __restrict__ A, const f16* __restrict__ B,
    const float* __restrict__ query, float* __restrict__ out) {
    __shared__ f16 As[2 * 128 * 32];
    __shared__ f16 Bs[2 * 128 * 32];
    const int tid = threadIdx.x, lane = tid & 63, w = tid >> 6;
    const int wm = w >> 1, wn = w & 1, lo = lane & 15, q4 = lane >> 4;
    const long tm = (long)blockIdx.y * 128, tn = (long)blockIdx.x * 128;
    const f16* Abase = A + tm * KDIM;
    const f16* Bbase = B + tn * KDIM;
    f32x4 acc[4][4] = {};
    const int srow = lane >> 2, sch = (lane & 3) * 8;

    for (int k0 = 0; k0 < KDIM; k0 += 64) {
#pragma unroll
        for (int j = 0; j < 4; ++j) {
            const int u = w * 4 + j, h = u & 1, Rb = u >> 1;
            const int base = h * 4096 + Rb * 512;
            const long grow = Rb * 16 + srow;
            const long gk = k0 + h * 32 + sch;
            stage16(&As[base], Abase + grow * KDIM + gk);
            stage16(&Bs[base], Bbase + grow * KDIM + gk);
        }
        __syncthreads();
        f16x8 af[4][2], bf[4][2];
#pragma unroll
        for (int s = 0; s < 2; ++s) {
#pragma unroll
            for (int mi = 0; mi < 4; ++mi)
                af[mi][s] = *(const f16x8*)&As[s * 4096 + (wm * 64 + mi * 16 + lo) * 32 + q4 * 8];
#pragma unroll
            for (int ni = 0; ni < 4; ++ni)
                bf[ni][s] = *(const f16x8*)&Bs[s * 4096 + (wn * 64 + ni * 16 + lo) * 32 + q4 * 8];
        }
#pragma unroll
        for (int s = 0; s < 2; ++s)
#pragma unroll
            for (int mi = 0; mi < 4; ++mi)
#pragma unroll
                for (int ni = 0; ni < 4; ++ni)
                    acc[mi][ni] = __builtin_amdgcn_mfma_f32_16x16x32_f16(af[mi][s], bf[ni][s], acc[mi][ni], 0, 0, 0);
        __syncthreads();
    }
#pragma unroll
    for (int mi = 0; mi < 4; ++mi)
#pragma unroll
        for (int ni = 0; ni < 4; ++ni) {
            long gc = tn + wn * 64 + ni * 16 + lo;
#pragma unroll
            for (int r = 0; r < 4; ++r) {
                long gr = tm + wm * 64 + mi * 16 + q4 * 4 + r;
                size_t idx = (size_t)gr * KDIM + gc;
                out[idx] = acc[mi][ni][r] + query[idx];
            }
        }
}

// ==== 64x64 bt-GEMM batched, BK=64: attn[b,l,m] = sum_j T[l,j]·qf16[m,j] ===
__global__ __launch_bounds__(256, 2) void attn_gemm(
    const f16* __restrict__ T, const f16* __restrict__ qf16, float* __restrict__ attn) {
    __shared__ f16 As[2 * 64 * 32];
    __shared__ f16 Bs[2 * 64 * 32];
    const int b = blockIdx.z;
    const long tl = (long)blockIdx.y * 64, tmm = (long)blockIdx.x * 64;
    const int tid = threadIdx.x, lane = tid & 63, w = tid >> 6;
    const int wm = w >> 1, wn = w & 1, lo = lane & 15, q4 = lane >> 4;
    const f16* Abase = T + ((long)b * FEAT + tl) * KDIM;
    const f16* Bbase = qf16 + ((long)b * FEAT + tmm) * KDIM;
    const int srow = lane >> 2, sch = (lane & 3) * 8;
    f32x4 acc[2][2] = {};
    for (int k0 = 0; k0 < KDIM; k0 += 64) {
#pragma unroll
        for (int j = 0; j < 2; ++j) {
            const int u = w * 2 + j, h = u & 1, Rb = u >> 1;
            const int base = h * 2048 + Rb * 512;
            const long grow = Rb * 16 + srow;
            const long gk = k0 + h * 32 + sch;
            stage16(&As[base], Abase + grow * KDIM + gk);
            stage16(&Bs[base], Bbase + grow * KDIM + gk);
        }
        __syncthreads();
        f16x8 af[2][2], bf[2][2];
#pragma unroll
        for (int s = 0; s < 2; ++s) {
#pragma unroll
            for (int mi = 0; mi < 2; ++mi)
                af[mi][s] = *(const f16x8*)&As[s * 2048 + (wm * 32 + mi * 16 + lo) * 32 + q4 * 8];
#pragma unroll
            for (int ni = 0; ni < 2; ++ni)
                bf[ni][s] = *(const f16x8*)&Bs[s * 2048 + (wn * 32 + ni * 16 + lo) * 32 + q4 * 8];
        }
#pragma unroll
        for (int s = 0; s < 2; ++s)
#pragma unroll
            for (int mi = 0; mi < 2; ++mi)
#pragma unroll
                for (int ni = 0; ni < 2; ++ni)
                    acc[mi][ni] = __builtin_amdgcn_mfma_f32_16x16x32_f16(af[mi][s], bf[ni][s], acc[mi][ni], 0, 0, 0);
        __syncthreads();
    }
#pragma unroll
    for (int mi = 0; mi < 2; ++mi)
#pragma unroll
        for (int ni = 0; ni < 2; ++ni) {
            long gm = tmm + wn * 32 + ni * 16 + lo;
#pragma unroll
            for (int r = 0; r < 4; ++r) {
                long gl = tl + wm * 32 + mi * 16 + q4 * 4 + r;
                attn[(long)b * (FEAT * FEAT) + gl * FEAT + gm] = acc[mi][ni][r];
            }
        }
}

// == 64x128 bt-GEMM batched, K=320 BK=64: U[b,l,j] = sum_m P[l,m]·qT[j,m] ===
__global__ __launch_bounds__(256, 2) void u_gemm(
    const f16* __restrict__ P, const f16* __restrict__ qT16, f16* __restrict__ U) {
    __shared__ f16 As[2 * 64 * 32];     // 8 KB
    __shared__ f16 Bs[2 * 128 * 32];    // 16 KB
    const int b = blockIdx.z;
    const long tl = (long)blockIdx.y * 64, to = (long)blockIdx.x * 128;
    const int tid = threadIdx.x, lane = tid & 63, w = tid >> 6;
    const int wm = w >> 1, wn = w & 1, lo = lane & 15, q4 = lane >> 4;
    const f16* Abase = P + ((long)b * FEAT + tl) * FEAT;
    const f16* Bbase = qT16 + ((long)b * NPTS + to) * FEAT;
    const int srow = lane >> 2, sch = (lane & 3) * 8;
    f32x4 acc[2][4] = {};
    for (int k0 = 0; k0 < FEAT; k0 += 64) {   // 5 iterations
#pragma unroll
        for (int j = 0; j < 2; ++j) {          // A: 8 wave-units
            const int u = w * 2 + j, h = u & 1, Rb = u >> 1;
            stage16(&As[h * 2048 + Rb * 512],
                    Abase + (long)(Rb * 16 + srow) * FEAT + k0 + h * 32 + sch);
        }
#pragma unroll
        for (int j = 0; j < 4; ++j) {          // B: 16 wave-units
            const int u = w * 4 + j, h = u & 1, Rb = u >> 1;
            stage16(&Bs[h * 4096 + Rb * 512],
                    Bbase + (long)(Rb * 16 + srow) * FEAT + k0 + h * 32 + sch);
        }
        __syncthreads();
        f16x8 af[2][2], bf[4][2];
#pragma unroll
        for (int s = 0; s < 2; ++s) {
#pragma unroll
            for (int mi = 0; mi < 2; ++mi)
                af[mi][s] = *(const f16x8*)&As[s * 2048 + (wm * 32 + mi * 16 + lo) * 32 + q4 * 8];
#pragma unroll
            for (int ni = 0; ni < 4; ++ni)
                bf[ni][s] = *(const f16x8*)&Bs[s * 4096 + (wn * 64 + ni * 16 + lo) * 32 + q4 * 8];
        }
#pragma unroll
        for (int s = 0; s < 2; ++s)
#pragma unroll
            for (int mi = 0; mi < 2; ++mi)
#pragma unroll
                for (int ni = 0; ni < 4; ++ni)
                    acc[mi][ni] = __builtin_amdgcn_mfma_f32_16x16x32_f16(af[mi][s], bf[ni][s], acc[mi][ni], 0, 0, 0);
        __syncthreads();
    }
#pragma unroll
    for (int mi = 0; mi < 2; ++mi)
#pragma unroll
        for (int ni = 0; ni < 4; ++ni) {
            long go = to + wn * 64 + ni * 16 + lo;
#pragma unroll
            for (int r = 0; r < 4; ++r) {
                long gl = tl + wm * 32 + mi * 16 + q4 * 4 + r;
                U[((long)b * FEAT + gl) * NPTS + go] = (f16)acc[mi][ni][r];
            }
        }
}

// ---------------- softmax over rows of 320, fp32 in, f16 probs out ---------
__global__ void softmax_k(const float* __restrict__ attn, f16* __restrict__ probs) {
    const int r = blockIdx.x * 4 + (threadIdx.x >> 6);   // 10240 rows
    const int lane = threadIdx.x & 63;
    const float* row = attn + (size_t)r * FEAT;
    float v[5];
    float mx = -1e30f;
#pragma unroll
    for (int j = 0; j < 5; ++j) { v[j] = row[lane + j * 64]; mx = fmaxf(mx, v[j]); }
#pragma unroll
    for (int off = 32; off; off >>= 1) mx = fmaxf(mx, __shfl_xor(mx, off, 64));
    float s = 0.f;
#pragma unroll
    for (int j = 0; j < 5; ++j) { v[j] = __expf(v[j] - mx); s += v[j]; }
#pragma unroll
    for (int off = 32; off; off >>= 1) s += __shfl_xor(s, off, 64);
    const float inv = 1.f / s;
    f16* prow = probs + (size_t)r * FEAT;
#pragma unroll
    for (int j = 0; j < 5; ++j) prow[lane + j * 64] = (f16)(v[j] * inv);
}

// ---------------- in-place LayerNorm over FEAT (stride NPTS) ---------------
__global__ void ln_k(float* __restrict__ out, const float* __restrict__ gamma,
                     const float* __restrict__ beta) {
    __shared__ float g[FEAT], bt[FEAT];
    const int tid = threadIdx.x;
    for (int i = tid; i < FEAT; i += 256) { g[i] = gamma[i]; bt[i] = beta[i]; }
    __syncthreads();
    const int col = blockIdx.x * 256 + tid;     // 65536 columns
    const int b = col >> 11, o = col & 2047;
    float* base = out + (size_t)b * (FEAT * NPTS) + o;
    float s = 0.f, ss = 0.f;
    for (int l = 0; l < FEAT; ++l) {
        float x = base[(size_t)l * NPTS];
        s += x; ss += x * x;
    }
    const float mu = s * (1.f / FEAT);
    const float var = ss * (1.f / FEAT) - mu * mu;
    const float rstd = rsqrtf(var + 1e-5f);
    for (int l = 0; l < FEAT; ++l) {
        float x = base[(size_t)l * NPTS];
        base[(size_t)l * NPTS] = (x - mu) * rstd * g[l] + bt[l];
    }
}

extern "C" void kernel_launch(void* const* d_in, const int* in_sizes, int n_in,
                              void* d_out, int out_size, void* d_ws, size_t ws_size,
                              hipStream_t stream) {
    const float* query   = (const float*)d_in[0];
    const float* support = (const float*)d_in[1];
    const float* Wq      = (const float*)d_in[2];
    const float* Wk      = (const float*)d_in[3];
    const float* Wv      = (const float*)d_in[4];
    const float* gamma   = (const float*)d_in[5];
    const float* beta    = (const float*)d_in[6];
    float* out = (float*)d_out;

    char* ws = (char*)d_ws;
    const size_t SZ_W = (size_t)KDIM * KDIM * sizeof(f16);   //  8,388,608
    const size_t SZ_X = (size_t)M1 * KDIM * sizeof(f16);     // 41,943,040
    f16* wqT  = (f16*)(ws);                        // [i,o]
    f16* wkT  = (f16*)(ws + SZ_W);                 // [j,o]
    f16* wv16 = (f16*)(ws + 2 * SZ_W);             // [o,j] straight
    f16* gt   = (f16*)(ws + 3 * SZ_W);             // Gt[j,i] = G[i,j]/TEMP
    f16* sf16 = (f16*)(ws + 4 * SZ_W);             // support f16 [b*320, i]
    f16* qf16 = (f16*)(ws + 4 * SZ_W + SZ_X);      // [b,m,j]
    f16* qT16 = (f16*)(ws + 4 * SZ_W + 2 * SZ_X);  // [b,j,m]
    f16* T    = (f16*)(ws + 4 * SZ_W + 3 * SZ_X);  // [b*320, j]
    // overlays (stream-ordered; originals dead by first write):
    float* attn = (float*)(ws);                    // 13.1 MB over wqT+wkT (dead after g_gemm)
    f16*   P    = qf16;                            // probs (qf16 dead after attn_gemm)
    f16*   U    = sf16;                            // U[b,l,j] (sf16 dead after t_gemm)

    const float inv_temp = 0.05590169943749474f;   // 1/sqrt(320)

    castT_k<<<dim3(32, 32, 2), 256, 0, stream>>>(Wq, Wk, wqT, wkT);
    cast_k<<<1024, 256, 0, stream>>>(Wv, wv16, (KDIM * KDIM) / 4);
    cast_k<<<2048, 256, 0, stream>>>(support, sf16, (M1 * KDIM) / 4);
    cast_q_dual<<<dim3(32, 5, 32), 256, 0, stream>>>(query, qf16, qT16);

    // Gt[j,i] = (1/TEMP) * sum_o WkT[j,o] * WqT[i,o]
    gemm128_f16<<<dim3(16, 16), 256, 0, stream>>>(wkT, wqT, gt, inv_temp);
    // T[(b,l), j] = sum_i sf16[(b,l), i] * Gt[j, i]
    gemm128_f16<<<dim3(16, 80), 256, 0, stream>>>(sf16, gt, T, 1.0f);
    // logits
    attn_gemm<<<dim3(5, 5, 32), 256, 0, stream>>>(T, qf16, attn);
    softmax_k<<<2560, 256, 0, stream>>>(attn, P);
    // U[b,l,j] = sum_m P[b,l,m] * qT16[b,j,m]
    u_gemm<<<dim3(16, 5, 32), 256, 0, stream>>>(P, qT16, U);
    // out = U * Wv^T + query
    gemm128_res<<<dim3(16, 80), 256, 0, stream>>>(U, wv16, query, out);
    ln_k<<<256, 256, 0, stream>>>(out, gamma, beta);
}